// Round 7
// baseline (245.249 us; speedup 1.0000x reference)
//
#include <hip/hip_runtime.h>
#include <math.h>

#define BINS 128

// ---------------- ws layout (float units) ----------------
// [0, 16384)       pp      pool partials [sb=(b*64+c)*8+part][16 cells]
// [16384, 16512)   s       sigmoid gate (2, 64)
// [16512, 16576)   lo_tab  int[64]
// [16576, 16640)   w_tab   float[64]
// [16640, 16642)   mm      mapped uints {min, max}
// [16648, 16776)   hist    uint[128]

__device__ __forceinline__ unsigned mapf(float f) {
    unsigned u = __float_as_uint(f);
    return (u & 0x80000000u) ? ~u : (u | 0x80000000u);
}
__device__ __forceinline__ float unmapf(unsigned m) {
    unsigned u = (m & 0x80000000u) ? (m & 0x7FFFFFFFu) : ~m;
    return __uint_as_float(u);
}
__device__ __forceinline__ float sel4(float g0, float g1, float g2, float g3, int k) {
    float a = (k & 1) ? g1 : g0;
    float b = (k & 1) ? g3 : g2;
    return (k & 2) ? b : a;
}

// ---- K1: pool partials. 1024 blocks; block sb covers 8 d-slices of slab (b,c). ----
__global__ __launch_bounds__(256) void pool_kernel(const float* __restrict__ x,
                                                   float* __restrict__ pp) {
    const int sb = blockIdx.x;
    const int t = threadIdx.x;
    const float4* xb = (const float4*)x + (size_t)sb * 8192;
    float a0 = 0.f, a1 = 0.f, a2 = 0.f, a3 = 0.f;
    #pragma unroll 2
    for (int n = 0; n < 32; n += 4) {
        float4 v0 = xb[(n + 0) * 256 + t]; a0 += (v0.x + v0.y) + (v0.z + v0.w);
        float4 v1 = xb[(n + 1) * 256 + t]; a1 += (v1.x + v1.y) + (v1.z + v1.w);
        float4 v2 = xb[(n + 2) * 256 + t]; a2 += (v2.x + v2.y) + (v2.z + v2.w);
        float4 v3 = xb[(n + 3) * 256 + t]; a3 += (v3.x + v3.y) + (v3.z + v3.w);
    }
    // ph = n&3 -> a0..a3 ; pw = lane bits {2,3} ; reduce lane bits {0,1,4,5}
    #pragma unroll
    for (int m = 0; m < 4; ++m) {
        const int msk = (m == 0) ? 1 : (m == 1) ? 2 : (m == 2) ? 16 : 32;
        a0 += __shfl_xor(a0, msk); a1 += __shfl_xor(a1, msk);
        a2 += __shfl_xor(a2, msk); a3 += __shfl_xor(a3, msk);
    }
    __shared__ float red[64];
    const int lane = t & 63, wave = t >> 6;
    if (lane < 16 && (lane & 3) == 0) {
        const int pw = lane >> 2;
        red[(0 * 4 + pw) * 4 + wave] = a0;
        red[(1 * 4 + pw) * 4 + wave] = a1;
        red[(2 * 4 + pw) * 4 + wave] = a2;
        red[(3 * 4 + pw) * 4 + wave] = a3;
    }
    __syncthreads();
    if (t < 16)
        pp[sb * 16 + t] = red[t * 4 + 0] + red[t * 4 + 1] + red[t * 4 + 2] + red[t * 4 + 3];
}

// ---- K2: w1 conv (from partials) + InstanceNorm + GELU + w2 conv + sigmoid + tables ----
__global__ __launch_bounds__(1024) void mid_kernel(const float* __restrict__ pp,
                                                   const float* __restrict__ w1,
                                                   const float* __restrict__ w2,
                                                   float* __restrict__ s_out,
                                                   int* __restrict__ lo_tab,
                                                   float* __restrict__ w_tab,
                                                   unsigned* __restrict__ mm,
                                                   unsigned* __restrict__ hist) {
    __shared__ float hs[2 * 8 * 64];
    const int t = threadIdx.x;
    const int b = t >> 9, cm = (t >> 6) & 7, sp = t & 63;
    const int off = (sp >> 4) * 32 + (sp & 15);   // part=2*pd -> pd*32 + cell
    const float* w1r = w1 + cm * 64;
    const float* ppb = pp + b * 64 * 128;
    float h = 0.f;
    for (int c = 0; c < 64; ++c)
        h += w1r[c] * (ppb[c * 128 + off] + ppb[c * 128 + 16 + off]);
    h *= (1.0f / 4096.0f);

    float s1 = h;
    #pragma unroll
    for (int m = 1; m <= 32; m <<= 1) s1 += __shfl_xor(s1, m);
    const float mu = s1 * (1.0f / 64.0f);
    float d = h - mu;
    float s2 = d * d;
    #pragma unroll
    for (int m = 1; m <= 32; m <<= 1) s2 += __shfl_xor(s2, m);
    const float var = s2 * (1.0f / 64.0f);
    const float hn = d / sqrtf(var + 1e-5f);
    hs[(b * 8 + cm) * 64 + sp] = 0.5f * hn * (1.0f + erff(hn * 0.70710678118654752440f));
    __syncthreads();
    if (t < 128) {
        const int bb = t >> 6, ss = t & 63;
        float acc = 0.f;
        #pragma unroll
        for (int c = 0; c < 8; ++c) acc += w2[c] * hs[(bb * 8 + c) * 64 + ss];
        s_out[t] = 1.0f / (1.0f + expf(-acc));
    }
    if (t < 64) {
        float coord = ((float)t + 0.5f) * 0.0625f - 0.5f;
        coord = fminf(fmaxf(coord, 0.0f), 3.0f);
        int lo = (int)floorf(coord);
        lo_tab[t] = lo;
        w_tab[t] = coord - (float)lo;
    }
    if (t == 0) { mm[0] = 0xFFFFFFFFu; mm[1] = 0u; }
    if (t >= 128 && t < 256) hist[t - 128] = 0u;
}

// Per-thread gate precompute. Grid 4096x256 -> base < 2^20, k-stride 2^20:
// h6 (bits 4-9) and d6 (bits 10-15) of the global float4 index are loop-
// invariant; k=0..3 -> batch 0, k=4..7 -> batch 1.
// Produces 8 registers: gate at this thread's 4 w-positions for b=0 and b=1.
#define PRECOMPUTE_GATES(base)                                                        \
    const int h6 = ((base) >> 4) & 63;                                                \
    const int d6 = ((base) >> 10) & 63;                                               \
    const int hl = llo[h6], dl = llo[d6];                                             \
    const float fh = lwt[h6], fd = lwt[d6];                                           \
    const int hh = min(hl + 1, 3), dh = min(dl + 1, 3);                               \
    const float w00 = (1.f - fd) * (1.f - fh), w01 = (1.f - fd) * fh;                 \
    const float w10 = fd * (1.f - fh), w11 = fd * fh;                                 \
    const int i00 = dl * 16 + hl * 4, i01 = dl * 16 + hh * 4;                         \
    const int i10 = dh * 16 + hl * 4, i11 = dh * 16 + hh * 4;                         \
    const int wbase = (t & 15) * 4;                                                   \
    const int wl0 = llo[wbase + 0], wl1 = llo[wbase + 1], wl2 = llo[wbase + 2], wl3 = llo[wbase + 3]; \
    const int wh0 = min(wl0 + 1, 3), wh1 = min(wl1 + 1, 3), wh2 = min(wl2 + 1, 3), wh3 = min(wl3 + 1, 3); \
    const float fw0 = lwt[wbase + 0], fw1 = lwt[wbase + 1], fw2 = lwt[wbase + 2], fw3 = lwt[wbase + 3]; \
    float a00, a01, a02, a03, a10, a11, a12, a13;                                     \
    {                                                                                 \
        const float* sb0 = ls;                                                        \
        float g0 = w00 * sb0[i00 + 0] + w01 * sb0[i01 + 0] + w10 * sb0[i10 + 0] + w11 * sb0[i11 + 0]; \
        float g1 = w00 * sb0[i00 + 1] + w01 * sb0[i01 + 1] + w10 * sb0[i10 + 1] + w11 * sb0[i11 + 1]; \
        float g2 = w00 * sb0[i00 + 2] + w01 * sb0[i01 + 2] + w10 * sb0[i10 + 2] + w11 * sb0[i11 + 2]; \
        float g3 = w00 * sb0[i00 + 3] + w01 * sb0[i01 + 3] + w10 * sb0[i10 + 3] + w11 * sb0[i11 + 3]; \
        float lo, hi;                                                                 \
        lo = sel4(g0, g1, g2, g3, wl0); hi = sel4(g0, g1, g2, g3, wh0); a00 = lo + fw0 * (hi - lo); \
        lo = sel4(g0, g1, g2, g3, wl1); hi = sel4(g0, g1, g2, g3, wh1); a01 = lo + fw1 * (hi - lo); \
        lo = sel4(g0, g1, g2, g3, wl2); hi = sel4(g0, g1, g2, g3, wh2); a02 = lo + fw2 * (hi - lo); \
        lo = sel4(g0, g1, g2, g3, wl3); hi = sel4(g0, g1, g2, g3, wh3); a03 = lo + fw3 * (hi - lo); \
        const float* sb1 = ls + 64;                                                   \
        g0 = w00 * sb1[i00 + 0] + w01 * sb1[i01 + 0] + w10 * sb1[i10 + 0] + w11 * sb1[i11 + 0]; \
        g1 = w00 * sb1[i00 + 1] + w01 * sb1[i01 + 1] + w10 * sb1[i10 + 1] + w11 * sb1[i11 + 1]; \
        g2 = w00 * sb1[i00 + 2] + w01 * sb1[i01 + 2] + w10 * sb1[i10 + 2] + w11 * sb1[i11 + 2]; \
        g3 = w00 * sb1[i00 + 3] + w01 * sb1[i01 + 3] + w10 * sb1[i10 + 3] + w11 * sb1[i11 + 3]; \
        lo = sel4(g0, g1, g2, g3, wl0); hi = sel4(g0, g1, g2, g3, wh0); a10 = lo + fw0 * (hi - lo); \
        lo = sel4(g0, g1, g2, g3, wl1); hi = sel4(g0, g1, g2, g3, wh1); a11 = lo + fw1 * (hi - lo); \
        lo = sel4(g0, g1, g2, g3, wl2); hi = sel4(g0, g1, g2, g3, wh2); a12 = lo + fw2 * (hi - lo); \
        lo = sel4(g0, g1, g2, g3, wl3); hi = sel4(g0, g1, g2, g3, wh3); a13 = lo + fw3 * (hi - lo); \
    }

// Issue ALL 8 global loads before any use (latency batching; the R6 fix).
#define LOAD8(xp)                                                                     \
    const float4 v0 = (xp)[0 * 1048576], v1 = (xp)[1 * 1048576];                      \
    const float4 v2 = (xp)[2 * 1048576], v3 = (xp)[3 * 1048576];                      \
    const float4 v4 = (xp)[4 * 1048576], v5 = (xp)[5 * 1048576];                      \
    const float4 v6 = (xp)[6 * 1048576], v7 = (xp)[7 * 1048576];

// ---- K3: global min/max of x * gate. MUST launch with <<<4096, 256>>>. ----
__global__ __launch_bounds__(256) void gated_minmax_kernel(const float* __restrict__ x,
                                                           const float* __restrict__ s,
                                                           const int* __restrict__ lo_tab,
                                                           const float* __restrict__ w_tab,
                                                           unsigned* __restrict__ mm) {
    __shared__ float ls[128];
    __shared__ int llo[64];
    __shared__ float lwt[64];
    __shared__ float red[8];
    const int t = threadIdx.x;
    if (t < 128) ls[t] = s[t];
    if (t < 64) { llo[t] = lo_tab[t]; lwt[t] = w_tab[t]; }
    __syncthreads();

    const int base = blockIdx.x * 256 + t;   // < 2^20
    PRECOMPUTE_GATES(base);

    const float4* xp = (const float4*)x + base;
    LOAD8(xp);

    float vmin = INFINITY, vmax = -INFINITY;
#define MM4(xv, b0, b1, b2, b3)                                                   \
    {                                                                             \
        float p0 = xv.x * b0, p1 = xv.y * b1, p2 = xv.z * b2, p3 = xv.w * b3;     \
        vmin = fminf(vmin, fminf(fminf(p0, p1), fminf(p2, p3)));                  \
        vmax = fmaxf(vmax, fmaxf(fmaxf(p0, p1), fmaxf(p2, p3)));                  \
    }
    MM4(v0, a00, a01, a02, a03); MM4(v1, a00, a01, a02, a03);
    MM4(v2, a00, a01, a02, a03); MM4(v3, a00, a01, a02, a03);
    MM4(v4, a10, a11, a12, a13); MM4(v5, a10, a11, a12, a13);
    MM4(v6, a10, a11, a12, a13); MM4(v7, a10, a11, a12, a13);
#undef MM4

    #pragma unroll
    for (int m = 1; m <= 32; m <<= 1) {
        vmin = fminf(vmin, __shfl_xor(vmin, m));
        vmax = fmaxf(vmax, __shfl_xor(vmax, m));
    }
    const int wave = t >> 6;
    if ((t & 63) == 0) { red[wave] = vmin; red[4 + wave] = vmax; }
    __syncthreads();
    if (t == 0) {
        float m0 = fminf(fminf(red[0], red[1]), fminf(red[2], red[3]));
        float M0 = fmaxf(fmaxf(red[4], red[5]), fmaxf(red[6], red[7]));
        atomicMin(&mm[0], mapf(m0));
        atomicMax(&mm[1], mapf(M0));
    }
}

// ---- K4: 128-bin histogram. MUST launch with <<<4096, 256>>>. ----
__global__ __launch_bounds__(256) void gated_hist_kernel(const float* __restrict__ x,
                                                         const float* __restrict__ s,
                                                         const int* __restrict__ lo_tab,
                                                         const float* __restrict__ w_tab,
                                                         const unsigned* __restrict__ mm,
                                                         unsigned* __restrict__ ghist) {
    __shared__ float ls[128];
    __shared__ int llo[64];
    __shared__ float lwt[64];
    __shared__ unsigned lh[BINS];
    const int t = threadIdx.x;
    if (t < 128) ls[t] = s[t];
    if (t < 64) { llo[t] = lo_tab[t]; lwt[t] = w_tab[t]; }
    if (t < BINS) lh[t] = 0u;
    __syncthreads();

    const int base = blockIdx.x * 256 + t;
    PRECOMPUTE_GATES(base);

    const float vmin = unmapf(mm[0]);
    const float vmax = unmapf(mm[1]);
    const float inv = 128.0f / (vmax - vmin + 1e-8f);
    const float4* xp = (const float4*)x + base;
    LOAD8(xp);

#define HIST4(xv, b0, b1, b2, b3)                                   \
    {                                                               \
        float p0 = xv.x * b0, p1 = xv.y * b1, p2 = xv.z * b2, p3 = xv.w * b3; \
        int i0 = (int)floorf((p0 - vmin) * inv);                    \
        int i1 = (int)floorf((p1 - vmin) * inv);                    \
        int i2 = (int)floorf((p2 - vmin) * inv);                    \
        int i3 = (int)floorf((p3 - vmin) * inv);                    \
        i0 = min(max(i0, 0), BINS - 1);                             \
        i1 = min(max(i1, 0), BINS - 1);                             \
        i2 = min(max(i2, 0), BINS - 1);                             \
        i3 = min(max(i3, 0), BINS - 1);                             \
        atomicAdd(&lh[i0], 1u);                                     \
        atomicAdd(&lh[i1], 1u);                                     \
        atomicAdd(&lh[i2], 1u);                                     \
        atomicAdd(&lh[i3], 1u);                                     \
    }

    HIST4(v0, a00, a01, a02, a03); HIST4(v1, a00, a01, a02, a03);
    HIST4(v2, a00, a01, a02, a03); HIST4(v3, a00, a01, a02, a03);
    HIST4(v4, a10, a11, a12, a13); HIST4(v5, a10, a11, a12, a13);
    HIST4(v6, a10, a11, a12, a13); HIST4(v7, a10, a11, a12, a13);
#undef HIST4

    __syncthreads();
    if (t < BINS) {
        unsigned c = lh[t];
        if (c) atomicAdd(&ghist[t], c);
    }
}

// ---- K5: entropy ----
__global__ __launch_bounds__(64) void entropy_kernel(const unsigned* __restrict__ ghist,
                                                     float* __restrict__ out) {
    const int t = threadIdx.x;
    float c0 = (float)ghist[t];
    float c1 = (float)ghist[t + 64];
    float s = c0 + c1;
    #pragma unroll
    for (int m = 1; m <= 32; m <<= 1) s += __shfl_xor(s, m);
    const float inv = 1.0f / (s + 1e-10f);
    float p0 = c0 * inv, p1 = c1 * inv;
    float e = p0 * log2f(p0 + 1e-10f) + p1 * log2f(p1 + 1e-10f);
    #pragma unroll
    for (int m = 1; m <= 32; m <<= 1) e += __shfl_xor(e, m);
    if (t == 0) out[0] = -e;
}

extern "C" void kernel_launch(void* const* d_in, const int* in_sizes, int n_in,
                              void* d_out, int out_size, void* d_ws, size_t ws_size,
                              hipStream_t stream) {
    (void)in_sizes; (void)n_in; (void)out_size; (void)ws_size;
    const float* x  = (const float*)d_in[0];
    const float* w1 = (const float*)d_in[1];
    const float* w2 = (const float*)d_in[2];
    float* out = (float*)d_out;
    float* ws  = (float*)d_ws;

    float* pp       = ws;                      // 16384
    float* s        = ws + 16384;              // 128
    int*   lo_tab   = (int*)(ws + 16512);      // 64
    float* w_tab    = ws + 16576;              // 64
    unsigned* mm    = (unsigned*)(ws + 16640); // 2
    unsigned* hist  = (unsigned*)(ws + 16648); // 128

    pool_kernel<<<1024, 256, 0, stream>>>(x, pp);
    mid_kernel<<<1, 1024, 0, stream>>>(pp, w1, w2, s, lo_tab, w_tab, mm, hist);
    gated_minmax_kernel<<<4096, 256, 0, stream>>>(x, s, lo_tab, w_tab, mm);
    gated_hist_kernel<<<4096, 256, 0, stream>>>(x, s, lo_tab, w_tab, mm, hist);
    entropy_kernel<<<1, 64, 0, stream>>>(hist, out);
}

// Round 8
// 154.249 us; speedup vs baseline: 1.5900x; 1.5900x over previous
//
#include <hip/hip_runtime.h>
#include <math.h>

#define BINS 128

// ---------------- ws layout (float units) ----------------
// [0, 16384)       pp      pool partials [sb=(b*64+c)*8+part][16 cells]
// [16384, 16512)   s       sigmoid gate (2, 64)
// [16640, 16642)   mm      mapped uints {min, max}
// [16648, 16776)   ghist   uint[128]

__device__ __forceinline__ unsigned mapf(float f) {
    unsigned u = __float_as_uint(f);
    return (u & 0x80000000u) ? ~u : (u | 0x80000000u);
}
__device__ __forceinline__ float unmapf(unsigned m) {
    unsigned u = (m & 0x80000000u) ? (m & 0x7FFFFFFFu) : ~m;
    return __uint_as_float(u);
}
__device__ __forceinline__ float sel4(float g0, float g1, float g2, float g3, int k) {
    float a = (k & 1) ? g1 : g0;
    float b = (k & 1) ? g3 : g2;
    return (k & 2) ? b : a;
}
// axis coord for upsample (align_corners=False, 64->4): lo, hi, frac
__device__ __forceinline__ void axgate(int v, int& lo, int& hi, float& fr) {
    float c = ((float)v + 0.5f) * 0.0625f - 0.5f;
    c = fminf(fmaxf(c, 0.0f), 3.0f);
    int l = (int)floorf(c);
    lo = l; hi = min(l + 1, 3); fr = c - (float)l;
}

// ---- K1: pool partials. 1024 blocks; block covers 8 d-slices of slab (b,c). ----
__global__ __launch_bounds__(256) void pool_kernel(const float* __restrict__ x,
                                                   float* __restrict__ pp) {
    const int bid = blockIdx.x;
    const int sb = (bid & 7) * 128 + (bid >> 3);   // XCD-contiguous
    const int t = threadIdx.x;
    const float4* xb = (const float4*)x + (size_t)sb * 8192;

    // batch A: n = 0..15, all loads issued before any use
    const float4 u0  = xb[ 0*256+t], u1  = xb[ 1*256+t], u2  = xb[ 2*256+t], u3  = xb[ 3*256+t];
    const float4 u4  = xb[ 4*256+t], u5  = xb[ 5*256+t], u6  = xb[ 6*256+t], u7  = xb[ 7*256+t];
    const float4 u8  = xb[ 8*256+t], u9  = xb[ 9*256+t], u10 = xb[10*256+t], u11 = xb[11*256+t];
    const float4 u12 = xb[12*256+t], u13 = xb[13*256+t], u14 = xb[14*256+t], u15 = xb[15*256+t];
    __builtin_amdgcn_sched_barrier(0);
    float a0 = 0.f, a1 = 0.f, a2 = 0.f, a3 = 0.f;
#define ACC(U, A) A += (U.x + U.y) + (U.z + U.w);
    ACC(u0,a0) ACC(u1,a1) ACC(u2,a2) ACC(u3,a3)
    ACC(u4,a0) ACC(u5,a1) ACC(u6,a2) ACC(u7,a3)
    ACC(u8,a0) ACC(u9,a1) ACC(u10,a2) ACC(u11,a3)
    ACC(u12,a0) ACC(u13,a1) ACC(u14,a2) ACC(u15,a3)
    // batch B: n = 16..31
    const float4 v0  = xb[16*256+t], v1  = xb[17*256+t], v2  = xb[18*256+t], v3  = xb[19*256+t];
    const float4 v4  = xb[20*256+t], v5  = xb[21*256+t], v6  = xb[22*256+t], v7  = xb[23*256+t];
    const float4 v8  = xb[24*256+t], v9  = xb[25*256+t], v10 = xb[26*256+t], v11 = xb[27*256+t];
    const float4 v12 = xb[28*256+t], v13 = xb[29*256+t], v14 = xb[30*256+t], v15 = xb[31*256+t];
    __builtin_amdgcn_sched_barrier(0);
    ACC(v0,a0) ACC(v1,a1) ACC(v2,a2) ACC(v3,a3)
    ACC(v4,a0) ACC(v5,a1) ACC(v6,a2) ACC(v7,a3)
    ACC(v8,a0) ACC(v9,a1) ACC(v10,a2) ACC(v11,a3)
    ACC(v12,a0) ACC(v13,a1) ACC(v14,a2) ACC(v15,a3)
#undef ACC

    // ph = n&3 -> a0..a3 ; pw = lane bits {2,3} ; reduce lane bits {0,1,4,5}
    #pragma unroll
    for (int m = 0; m < 4; ++m) {
        const int msk = (m == 0) ? 1 : (m == 1) ? 2 : (m == 2) ? 16 : 32;
        a0 += __shfl_xor(a0, msk); a1 += __shfl_xor(a1, msk);
        a2 += __shfl_xor(a2, msk); a3 += __shfl_xor(a3, msk);
    }
    __shared__ float red[64];
    const int lane = t & 63, wave = t >> 6;
    if (lane < 16 && (lane & 3) == 0) {
        const int pw = lane >> 2;
        red[(0 * 4 + pw) * 4 + wave] = a0;
        red[(1 * 4 + pw) * 4 + wave] = a1;
        red[(2 * 4 + pw) * 4 + wave] = a2;
        red[(3 * 4 + pw) * 4 + wave] = a3;
    }
    __syncthreads();
    if (t < 16)
        pp[sb * 16 + t] = red[t * 4 + 0] + red[t * 4 + 1] + red[t * 4 + 2] + red[t * 4 + 3];
}

// ---- K2: w1 conv (from partials) + InstanceNorm + GELU + w2 conv + sigmoid + init ----
__global__ __launch_bounds__(1024) void mid_kernel(const float* __restrict__ pp,
                                                   const float* __restrict__ w1,
                                                   const float* __restrict__ w2,
                                                   float* __restrict__ s_out,
                                                   unsigned* __restrict__ mm,
                                                   unsigned* __restrict__ hist) {
    __shared__ float hs[2 * 8 * 64];
    const int t = threadIdx.x;
    const int b = t >> 9, cm = (t >> 6) & 7, sp = t & 63;
    const int off = (sp >> 4) * 32 + (sp & 15);   // part=2*pd -> pd*32 + cell
    const float* w1r = w1 + cm * 64;
    const float* ppb = pp + b * 64 * 128;
    float h = 0.f;
    for (int c = 0; c < 64; ++c)
        h += w1r[c] * (ppb[c * 128 + off] + ppb[c * 128 + 16 + off]);
    h *= (1.0f / 4096.0f);

    float s1 = h;
    #pragma unroll
    for (int m = 1; m <= 32; m <<= 1) s1 += __shfl_xor(s1, m);
    const float mu = s1 * (1.0f / 64.0f);
    float d = h - mu;
    float s2 = d * d;
    #pragma unroll
    for (int m = 1; m <= 32; m <<= 1) s2 += __shfl_xor(s2, m);
    const float var = s2 * (1.0f / 64.0f);
    const float hn = d / sqrtf(var + 1e-5f);
    hs[(b * 8 + cm) * 64 + sp] = 0.5f * hn * (1.0f + erff(hn * 0.70710678118654752440f));
    __syncthreads();
    if (t < 128) {
        const int bb = t >> 6, ss = t & 63;
        float acc = 0.f;
        #pragma unroll
        for (int c = 0; c < 8; ++c) acc += w2[c] * hs[(bb * 8 + c) * 64 + ss];
        s_out[t] = 1.0f / (1.0f + expf(-acc));
    }
    if (t == 0) { mm[0] = 0xFFFFFFFFu; mm[1] = 0u; }
    if (t >= 128 && t < 256) hist[t - 128] = 0u;
}

// Shared prologue for K3/K4: chunk decode, 16 coalesced batched loads,
// rowg table build. chunk = 4096 float4 = 4 d-slices of slab (b,c).
#define CHUNK_PROLOGUE(ZERO_LH)                                                       \
    const int t = threadIdx.x;                                                        \
    const int bid = blockIdx.x;                                                       \
    const int swz = (bid & 7) * 256 + (bid >> 3);   /* XCD-contiguous */              \
    const int b = swz >> 10;                                                          \
    const int dq = swz & 15;                                                          \
    const float4* xp = (const float4*)x + (size_t)swz * 4096;                         \
    const float4 u0  = xp[ 0*256+t], u1  = xp[ 1*256+t], u2  = xp[ 2*256+t], u3  = xp[ 3*256+t]; \
    const float4 u4  = xp[ 4*256+t], u5  = xp[ 5*256+t], u6  = xp[ 6*256+t], u7  = xp[ 7*256+t]; \
    const float4 u8  = xp[ 8*256+t], u9  = xp[ 9*256+t], u10 = xp[10*256+t], u11 = xp[11*256+t]; \
    const float4 u12 = xp[12*256+t], u13 = xp[13*256+t], u14 = xp[14*256+t], u15 = xp[15*256+t]; \
    __builtin_amdgcn_sched_barrier(0);                                                \
    if (t < 64) ls64[t] = s[b * 64 + t];                                              \
    ZERO_LH                                                                           \
    __syncthreads();                                                                  \
    {   /* rowg[t]: bilinear(d,h) gate at 4 w-corners; d = dq*4 + (t>>6), h = t&63 */ \
        int dl, dh2; float fd; axgate(dq * 4 + (t >> 6), dl, dh2, fd);                \
        int hl, hh2; float fh; axgate(t & 63, hl, hh2, fh);                           \
        const float w00 = (1.f - fd) * (1.f - fh), w01 = (1.f - fd) * fh;             \
        const float w10 = fd * (1.f - fh), w11 = fd * fh;                             \
        const int i00 = dl * 16 + hl * 4, i01 = dl * 16 + hh2 * 4;                    \
        const int i10 = dh2 * 16 + hl * 4, i11 = dh2 * 16 + hh2 * 4;                  \
        float g0 = w00 * ls64[i00 + 0] + w01 * ls64[i01 + 0] + w10 * ls64[i10 + 0] + w11 * ls64[i11 + 0]; \
        float g1 = w00 * ls64[i00 + 1] + w01 * ls64[i01 + 1] + w10 * ls64[i10 + 1] + w11 * ls64[i11 + 1]; \
        float g2 = w00 * ls64[i00 + 2] + w01 * ls64[i01 + 2] + w10 * ls64[i10 + 2] + w11 * ls64[i11 + 2]; \
        float g3 = w00 * ls64[i00 + 3] + w01 * ls64[i01 + 3] + w10 * ls64[i10 + 3] + w11 * ls64[i11 + 3]; \
        rowg[t] = make_float4(g0, g1, g2, g3);                                        \
    }                                                                                 \
    __syncthreads();                                                                  \
    /* per-thread w constants: w = (t&15)*4 + c, fixed across k */                    \
    int wl0, wh0, wl1, wh1, wl2, wh2, wl3, wh3;                                       \
    float fw0, fw1, fw2, fw3;                                                         \
    {                                                                                 \
        const int wb = (t & 15) * 4;                                                  \
        axgate(wb + 0, wl0, wh0, fw0); axgate(wb + 1, wl1, wh1, fw1);                 \
        axgate(wb + 2, wl2, wh2, fw2); axgate(wb + 3, wl3, wh3, fw3);                 \
    }                                                                                 \
    const int rbase = t >> 4;

#define GATE4(K, G0, G1, G2, G3)                                                      \
    float G0, G1, G2, G3;                                                             \
    {                                                                                 \
        float4 rg = rowg[(K) * 16 + rbase];                                           \
        float lo, hi;                                                                 \
        lo = sel4(rg.x, rg.y, rg.z, rg.w, wl0); hi = sel4(rg.x, rg.y, rg.z, rg.w, wh0); G0 = lo + fw0 * (hi - lo); \
        lo = sel4(rg.x, rg.y, rg.z, rg.w, wl1); hi = sel4(rg.x, rg.y, rg.z, rg.w, wh1); G1 = lo + fw1 * (hi - lo); \
        lo = sel4(rg.x, rg.y, rg.z, rg.w, wl2); hi = sel4(rg.x, rg.y, rg.z, rg.w, wh2); G2 = lo + fw2 * (hi - lo); \
        lo = sel4(rg.x, rg.y, rg.z, rg.w, wl3); hi = sel4(rg.x, rg.y, rg.z, rg.w, wh3); G3 = lo + fw3 * (hi - lo); \
    }

// ---- K3: global min/max of x * gate. MUST launch with <<<2048, 256>>>. ----
__global__ __launch_bounds__(256) void gated_minmax_kernel(const float* __restrict__ x,
                                                           const float* __restrict__ s,
                                                           unsigned* __restrict__ mm) {
    __shared__ float ls64[64];
    __shared__ float4 rowg[256];
    __shared__ float red[8];
    CHUNK_PROLOGUE()

    float vmin = INFINITY, vmax = -INFINITY;
#define MM1(K, U)                                                                     \
    {                                                                                 \
        GATE4(K, g0, g1, g2, g3);                                                     \
        float p0 = U.x * g0, p1 = U.y * g1, p2 = U.z * g2, p3 = U.w * g3;             \
        vmin = fminf(vmin, fminf(fminf(p0, p1), fminf(p2, p3)));                      \
        vmax = fmaxf(vmax, fmaxf(fmaxf(p0, p1), fmaxf(p2, p3)));                      \
    }
    MM1(0,u0) MM1(1,u1) MM1(2,u2) MM1(3,u3) MM1(4,u4) MM1(5,u5) MM1(6,u6) MM1(7,u7)
    MM1(8,u8) MM1(9,u9) MM1(10,u10) MM1(11,u11) MM1(12,u12) MM1(13,u13) MM1(14,u14) MM1(15,u15)
#undef MM1

    #pragma unroll
    for (int m = 1; m <= 32; m <<= 1) {
        vmin = fminf(vmin, __shfl_xor(vmin, m));
        vmax = fmaxf(vmax, __shfl_xor(vmax, m));
    }
    const int wave = t >> 6;
    if ((t & 63) == 0) { red[wave] = vmin; red[4 + wave] = vmax; }
    __syncthreads();
    if (t == 0) {
        float m0 = fminf(fminf(red[0], red[1]), fminf(red[2], red[3]));
        float M0 = fmaxf(fmaxf(red[4], red[5]), fmaxf(red[6], red[7]));
        atomicMin(&mm[0], mapf(m0));
        atomicMax(&mm[1], mapf(M0));
    }
}

// ---- K4: 128-bin histogram. MUST launch with <<<2048, 256>>>. ----
__global__ __launch_bounds__(256) void gated_hist_kernel(const float* __restrict__ x,
                                                         const float* __restrict__ s,
                                                         const unsigned* __restrict__ mm,
                                                         unsigned* __restrict__ ghist) {
    __shared__ float ls64[64];
    __shared__ float4 rowg[256];
    __shared__ unsigned lh[BINS * 8];   // 8-column privatized
    CHUNK_PROLOGUE(for (int j = t; j < BINS * 8; j += 256) lh[j] = 0u;)

    const float vmin = unmapf(mm[0]);
    const float vmax = unmapf(mm[1]);
    const float inv = 128.0f / (vmax - vmin + 1e-8f);
    const int col = t & 7;

#define H1(K, U)                                                                      \
    {                                                                                 \
        GATE4(K, g0, g1, g2, g3);                                                     \
        float p0 = U.x * g0, p1 = U.y * g1, p2 = U.z * g2, p3 = U.w * g3;             \
        int i0 = (int)((p0 - vmin) * inv);  /* p >= vmin -> trunc == floor */         \
        int i1 = (int)((p1 - vmin) * inv);                                            \
        int i2 = (int)((p2 - vmin) * inv);                                            \
        int i3 = (int)((p3 - vmin) * inv);                                            \
        i0 = min(i0, BINS - 1); i1 = min(i1, BINS - 1);                               \
        i2 = min(i2, BINS - 1); i3 = min(i3, BINS - 1);                               \
        atomicAdd(&lh[i0 * 8 + col], 1u);                                             \
        atomicAdd(&lh[i1 * 8 + col], 1u);                                             \
        atomicAdd(&lh[i2 * 8 + col], 1u);                                             \
        atomicAdd(&lh[i3 * 8 + col], 1u);                                             \
    }
    H1(0,u0) H1(1,u1) H1(2,u2) H1(3,u3) H1(4,u4) H1(5,u5) H1(6,u6) H1(7,u7)
    H1(8,u8) H1(9,u9) H1(10,u10) H1(11,u11) H1(12,u12) H1(13,u13) H1(14,u14) H1(15,u15)
#undef H1

    __syncthreads();
    if (t < BINS) {
        unsigned sum = 0;
        #pragma unroll
        for (int j = 0; j < 8; ++j) sum += lh[t * 8 + j];
        if (sum) atomicAdd(&ghist[t], sum);
    }
}

// ---- K5: entropy ----
__global__ __launch_bounds__(64) void entropy_kernel(const unsigned* __restrict__ ghist,
                                                     float* __restrict__ out) {
    const int t = threadIdx.x;
    float c0 = (float)ghist[t];
    float c1 = (float)ghist[t + 64];
    float s = c0 + c1;
    #pragma unroll
    for (int m = 1; m <= 32; m <<= 1) s += __shfl_xor(s, m);
    const float inv = 1.0f / (s + 1e-10f);
    float p0 = c0 * inv, p1 = c1 * inv;
    float e = p0 * log2f(p0 + 1e-10f) + p1 * log2f(p1 + 1e-10f);
    #pragma unroll
    for (int m = 1; m <= 32; m <<= 1) e += __shfl_xor(e, m);
    if (t == 0) out[0] = -e;
}

extern "C" void kernel_launch(void* const* d_in, const int* in_sizes, int n_in,
                              void* d_out, int out_size, void* d_ws, size_t ws_size,
                              hipStream_t stream) {
    (void)in_sizes; (void)n_in; (void)out_size; (void)ws_size;
    const float* x  = (const float*)d_in[0];
    const float* w1 = (const float*)d_in[1];
    const float* w2 = (const float*)d_in[2];
    float* out = (float*)d_out;
    float* ws  = (float*)d_ws;

    float* pp       = ws;                      // 16384
    float* s        = ws + 16384;              // 128
    unsigned* mm    = (unsigned*)(ws + 16640); // 2
    unsigned* hist  = (unsigned*)(ws + 16648); // 128

    pool_kernel<<<1024, 256, 0, stream>>>(x, pp);
    mid_kernel<<<1, 1024, 0, stream>>>(pp, w1, w2, s, mm, hist);
    gated_minmax_kernel<<<2048, 256, 0, stream>>>(x, s, mm);
    gated_hist_kernel<<<2048, 256, 0, stream>>>(x, s, mm, hist);
    entropy_kernel<<<1, 64, 0, stream>>>(hist, out);
}

// Round 9
// 98.384 us; speedup vs baseline: 2.4928x; 1.5678x over previous
//
#include <hip/hip_runtime.h>
#include <math.h>

#define BINS 128

// ---------------- ws layout (float units) ----------------
// [0, 8192)        p       pooled means (B=2, C=64, sp=64)
// [8192, 8320)     s       sigmoid gate (2, 64)
// [8448, 8450)     mm      mapped uints {min, max}
// [8456, 8584)     ghist   uint[128]

__device__ __forceinline__ unsigned mapf(float f) {
    unsigned u = __float_as_uint(f);
    return (u & 0x80000000u) ? ~u : (u | 0x80000000u);
}
__device__ __forceinline__ float unmapf(unsigned m) {
    unsigned u = (m & 0x80000000u) ? (m & 0x7FFFFFFFu) : ~m;
    return __uint_as_float(u);
}
__device__ __forceinline__ float sel4(float g0, float g1, float g2, float g3, int k) {
    float a = (k & 1) ? g1 : g0;
    float b = (k & 1) ? g3 : g2;
    return (k & 2) ? b : a;
}
// axis coord for trilinear upsample (align_corners=False, 4 -> 64)
__device__ __forceinline__ void axgate(int v, int& lo, int& hi, float& fr) {
    float c = ((float)v + 0.5f) * 0.0625f - 0.5f;
    c = fminf(fmaxf(c, 0.0f), 3.0f);
    int l = (int)floorf(c);
    lo = l; hi = min(l + 1, 3); fr = c - (float)l;
}

// ---- K1: adaptive avg pool (R1-proven). 512 blocks, one 16x64x64 slab each. ----
__global__ __launch_bounds__(256) void pool_kernel(const float* __restrict__ x,
                                                   float* __restrict__ p) {
    const int blk = blockIdx.x;
    const int t = threadIdx.x;
    const float4* xb = (const float4*)x + (size_t)blk * 16384;
    float acc0 = 0.f, acc1 = 0.f, acc2 = 0.f, acc3 = 0.f;
    for (int n = 0; n < 64; n += 4) {
        float4 v0 = xb[(n + 0) * 256 + t]; acc0 += (v0.x + v0.y) + (v0.z + v0.w);
        float4 v1 = xb[(n + 1) * 256 + t]; acc1 += (v1.x + v1.y) + (v1.z + v1.w);
        float4 v2 = xb[(n + 2) * 256 + t]; acc2 += (v2.x + v2.y) + (v2.z + v2.w);
        float4 v3 = xb[(n + 3) * 256 + t]; acc3 += (v3.x + v3.y) + (v3.z + v3.w);
    }
    #pragma unroll
    for (int m = 0; m < 4; ++m) {
        int mask = (m == 0) ? 1 : (m == 1) ? 2 : (m == 2) ? 16 : 32;
        acc0 += __shfl_xor(acc0, mask);
        acc1 += __shfl_xor(acc1, mask);
        acc2 += __shfl_xor(acc2, mask);
        acc3 += __shfl_xor(acc3, mask);
    }
    __shared__ float red[64];
    const int lane = t & 63, wave = t >> 6;
    if (lane < 16 && (lane & 3) == 0) {
        const int pw = lane >> 2;
        red[(0 * 4 + pw) * 4 + wave] = acc0;
        red[(1 * 4 + pw) * 4 + wave] = acc1;
        red[(2 * 4 + pw) * 4 + wave] = acc2;
        red[(3 * 4 + pw) * 4 + wave] = acc3;
    }
    __syncthreads();
    if (t < 16)
        p[blk * 16 + t] = (red[t * 4 + 0] + red[t * 4 + 1] + red[t * 4 + 2] + red[t * 4 + 3]) * (1.0f / 4096.0f);
}

// ---- K2: w1 conv + InstanceNorm + GELU + w2 conv + sigmoid + init (R1-proven) ----
__global__ __launch_bounds__(1024) void mid_kernel(const float* __restrict__ p,
                                                   const float* __restrict__ w1,
                                                   const float* __restrict__ w2,
                                                   float* __restrict__ s_out,
                                                   unsigned* __restrict__ mm,
                                                   unsigned* __restrict__ hist) {
    __shared__ float hs[2 * 8 * 64];
    const int t = threadIdx.x;
    const int b = t >> 9, cm = (t >> 6) & 7, sp = t & 63;
    float h = 0.f;
    const float* pb = p + b * 64 * 64 + sp;
    const float* w1r = w1 + cm * 64;
    for (int c = 0; c < 64; ++c) h += w1r[c] * pb[c * 64];
    float s1 = h;
    #pragma unroll
    for (int m = 1; m <= 32; m <<= 1) s1 += __shfl_xor(s1, m);
    const float mu = s1 * (1.0f / 64.0f);
    float d = h - mu;
    float s2 = d * d;
    #pragma unroll
    for (int m = 1; m <= 32; m <<= 1) s2 += __shfl_xor(s2, m);
    const float var = s2 * (1.0f / 64.0f);
    const float hn = d / sqrtf(var + 1e-5f);
    hs[(b * 8 + cm) * 64 + sp] = 0.5f * hn * (1.0f + erff(hn * 0.70710678118654752440f));
    __syncthreads();
    if (t < 128) {
        const int bb = t >> 6, ss = t & 63;
        float acc = 0.f;
        #pragma unroll
        for (int c = 0; c < 8; ++c) acc += w2[c] * hs[(bb * 8 + c) * 64 + ss];
        s_out[t] = 1.0f / (1.0f + expf(-acc));
    }
    if (t == 0) { mm[0] = 0xFFFFFFFFu; mm[1] = 0u; }
    if (t >= 128 && t < 256) hist[t - 128] = 0u;
}

// ---------- shared machinery for the two streaming passes ----------
// 512 blocks, 4 chunks/block, chunk = 4096 float4 = 64 KB (one (b,c,dq) quad).
// Block i: xcd = i&7 owns chunks [xcd*256, xcd*256+256); j = i>>3 in [0,64);
// chunks = xcd*256 + j*4 + {0..3}.  b = swz>>10 is block-invariant.

#define PASS_SETUP()                                                                  \
    const int t = threadIdx.x;                                                        \
    const int bid = blockIdx.x;                                                       \
    const int cbase = (bid & 7) * 256 + (bid >> 3) * 4;                               \
    const int b = cbase >> 10;                                                        \
    if (t < 64) ls64[t] = s[b * 64 + t];                                              \
    /* per-thread w constants: w = (t&15)*4 + c */                                    \
    int wl0, wh0, wl1, wh1, wl2, wh2, wl3, wh3;                                       \
    float fw0, fw1, fw2, fw3;                                                         \
    {                                                                                 \
        const int wb = (t & 15) * 4;                                                  \
        axgate(wb + 0, wl0, wh0, fw0); axgate(wb + 1, wl1, wh1, fw1);                 \
        axgate(wb + 2, wl2, wh2, fw2); axgate(wb + 3, wl3, wh3, fw3);                 \
    }                                                                                 \
    int hlL, hhL; float fhL; axgate(t & 63, hlL, hhL, fhL);                           \
    const int rbase = t >> 4;

// Per-chunk: rebuild rowg (bilinear d,h gate at the 4 w-corners) then 16 loads.
#define CHUNK_HEAD(IT)                                                                \
    const int swz = cbase + (IT);                                                     \
    const int dq = swz & 15;                                                          \
    const float4* xp = (const float4*)x + (size_t)swz * 4096;                         \
    __syncthreads();   /* prior-iter rowg readers done */                             \
    {                                                                                 \
        int dl, dh2; float fd; axgate(dq * 4 + (t >> 6), dl, dh2, fd);                \
        const float w00 = (1.f - fd) * (1.f - fhL), w01 = (1.f - fd) * fhL;           \
        const float w10 = fd * (1.f - fhL), w11 = fd * fhL;                           \
        const int i00 = dl * 16 + hlL * 4, i01 = dl * 16 + hhL * 4;                   \
        const int i10 = dh2 * 16 + hlL * 4, i11 = dh2 * 16 + hhL * 4;                 \
        float g0 = w00 * ls64[i00 + 0] + w01 * ls64[i01 + 0] + w10 * ls64[i10 + 0] + w11 * ls64[i11 + 0]; \
        float g1 = w00 * ls64[i00 + 1] + w01 * ls64[i01 + 1] + w10 * ls64[i10 + 1] + w11 * ls64[i11 + 1]; \
        float g2 = w00 * ls64[i00 + 2] + w01 * ls64[i01 + 2] + w10 * ls64[i10 + 2] + w11 * ls64[i11 + 2]; \
        float g3 = w00 * ls64[i00 + 3] + w01 * ls64[i01 + 3] + w10 * ls64[i10 + 3] + w11 * ls64[i11 + 3]; \
        rowg[t] = make_float4(g0, g1, g2, g3);                                        \
    }                                                                                 \
    __syncthreads();                                                                  \
    const float4 u0  = xp[ 0*256+t], u1  = xp[ 1*256+t], u2  = xp[ 2*256+t], u3  = xp[ 3*256+t]; \
    const float4 u4  = xp[ 4*256+t], u5  = xp[ 5*256+t], u6  = xp[ 6*256+t], u7  = xp[ 7*256+t]; \
    const float4 u8  = xp[ 8*256+t], u9  = xp[ 9*256+t], u10 = xp[10*256+t], u11 = xp[11*256+t]; \
    const float4 u12 = xp[12*256+t], u13 = xp[13*256+t], u14 = xp[14*256+t], u15 = xp[15*256+t]; \
    __builtin_amdgcn_sched_barrier(0);

#define GATE4(K, G0, G1, G2, G3)                                                      \
    float G0, G1, G2, G3;                                                             \
    {                                                                                 \
        float4 rg = rowg[(K) * 16 + rbase];                                           \
        float lo, hi;                                                                 \
        lo = sel4(rg.x, rg.y, rg.z, rg.w, wl0); hi = sel4(rg.x, rg.y, rg.z, rg.w, wh0); G0 = lo + fw0 * (hi - lo); \
        lo = sel4(rg.x, rg.y, rg.z, rg.w, wl1); hi = sel4(rg.x, rg.y, rg.z, rg.w, wh1); G1 = lo + fw1 * (hi - lo); \
        lo = sel4(rg.x, rg.y, rg.z, rg.w, wl2); hi = sel4(rg.x, rg.y, rg.z, rg.w, wh2); G2 = lo + fw2 * (hi - lo); \
        lo = sel4(rg.x, rg.y, rg.z, rg.w, wl3); hi = sel4(rg.x, rg.y, rg.z, rg.w, wh3); G3 = lo + fw3 * (hi - lo); \
    }

// ---- K3: global min/max of x * gate. MUST launch with <<<512, 256>>>. ----
__global__ __launch_bounds__(256) void gated_minmax_kernel(const float* __restrict__ x,
                                                           const float* __restrict__ s,
                                                           unsigned* __restrict__ mm) {
    __shared__ float ls64[64];
    __shared__ float4 rowg[256];
    __shared__ float red[8];
    PASS_SETUP()

    float vmin = INFINITY, vmax = -INFINITY;
    #pragma unroll
    for (int it = 0; it < 4; ++it) {
        CHUNK_HEAD(it)
#define MM1(K, U)                                                                     \
        {                                                                             \
            GATE4(K, g0, g1, g2, g3);                                                 \
            float p0 = U.x * g0, p1 = U.y * g1, p2 = U.z * g2, p3 = U.w * g3;         \
            vmin = fminf(vmin, fminf(fminf(p0, p1), fminf(p2, p3)));                  \
            vmax = fmaxf(vmax, fmaxf(fmaxf(p0, p1), fmaxf(p2, p3)));                  \
        }
        MM1(0,u0) MM1(1,u1) MM1(2,u2) MM1(3,u3) MM1(4,u4) MM1(5,u5) MM1(6,u6) MM1(7,u7)
        MM1(8,u8) MM1(9,u9) MM1(10,u10) MM1(11,u11) MM1(12,u12) MM1(13,u13) MM1(14,u14) MM1(15,u15)
#undef MM1
    }

    #pragma unroll
    for (int m = 1; m <= 32; m <<= 1) {
        vmin = fminf(vmin, __shfl_xor(vmin, m));
        vmax = fmaxf(vmax, __shfl_xor(vmax, m));
    }
    const int wave = t >> 6;
    if ((t & 63) == 0) { red[wave] = vmin; red[4 + wave] = vmax; }
    __syncthreads();
    if (t == 0) {
        float m0 = fminf(fminf(red[0], red[1]), fminf(red[2], red[3]));
        float M0 = fmaxf(fmaxf(red[4], red[5]), fmaxf(red[6], red[7]));
        atomicMin(&mm[0], mapf(m0));
        atomicMax(&mm[1], mapf(M0));
    }
}

// ---- K4: 128-bin histogram. MUST launch with <<<512, 256>>>. ----
__global__ __launch_bounds__(256) void gated_hist_kernel(const float* __restrict__ x,
                                                         const float* __restrict__ s,
                                                         const unsigned* __restrict__ mm,
                                                         unsigned* __restrict__ ghist) {
    __shared__ float ls64[64];
    __shared__ float4 rowg[256];
    __shared__ unsigned lh[BINS];
    PASS_SETUP()
    if (t < BINS) lh[t] = 0u;

    const float vmin = unmapf(mm[0]);
    const float vmax = unmapf(mm[1]);
    const float inv = 128.0f / (vmax - vmin + 1e-8f);

    #pragma unroll
    for (int it = 0; it < 4; ++it) {
        CHUNK_HEAD(it)
#define H1(K, U)                                                                      \
        {                                                                             \
            GATE4(K, g0, g1, g2, g3);                                                 \
            float p0 = U.x * g0, p1 = U.y * g1, p2 = U.z * g2, p3 = U.w * g3;         \
            int i0 = (int)floorf((p0 - vmin) * inv);                                  \
            int i1 = (int)floorf((p1 - vmin) * inv);                                  \
            int i2 = (int)floorf((p2 - vmin) * inv);                                  \
            int i3 = (int)floorf((p3 - vmin) * inv);                                  \
            i0 = min(max(i0, 0), BINS - 1); i1 = min(max(i1, 0), BINS - 1);           \
            i2 = min(max(i2, 0), BINS - 1); i3 = min(max(i3, 0), BINS - 1);           \
            atomicAdd(&lh[i0], 1u);                                                   \
            atomicAdd(&lh[i1], 1u);                                                   \
            atomicAdd(&lh[i2], 1u);                                                   \
            atomicAdd(&lh[i3], 1u);                                                   \
        }
        H1(0,u0) H1(1,u1) H1(2,u2) H1(3,u3) H1(4,u4) H1(5,u5) H1(6,u6) H1(7,u7)
        H1(8,u8) H1(9,u9) H1(10,u10) H1(11,u11) H1(12,u12) H1(13,u13) H1(14,u14) H1(15,u15)
#undef H1
    }

    __syncthreads();
    if (t < BINS) {
        unsigned c = lh[t];
        if (c) atomicAdd(&ghist[t], c);
    }
}

// ---- K5: entropy ----
__global__ __launch_bounds__(64) void entropy_kernel(const unsigned* __restrict__ ghist,
                                                     float* __restrict__ out) {
    const int t = threadIdx.x;
    float c0 = (float)ghist[t];
    float c1 = (float)ghist[t + 64];
    float s = c0 + c1;
    #pragma unroll
    for (int m = 1; m <= 32; m <<= 1) s += __shfl_xor(s, m);
    const float inv = 1.0f / (s + 1e-10f);
    float p0 = c0 * inv, p1 = c1 * inv;
    float e = p0 * log2f(p0 + 1e-10f) + p1 * log2f(p1 + 1e-10f);
    #pragma unroll
    for (int m = 1; m <= 32; m <<= 1) e += __shfl_xor(e, m);
    if (t == 0) out[0] = -e;
}

extern "C" void kernel_launch(void* const* d_in, const int* in_sizes, int n_in,
                              void* d_out, int out_size, void* d_ws, size_t ws_size,
                              hipStream_t stream) {
    (void)in_sizes; (void)n_in; (void)out_size; (void)ws_size;
    const float* x  = (const float*)d_in[0];
    const float* w1 = (const float*)d_in[1];
    const float* w2 = (const float*)d_in[2];
    float* out = (float*)d_out;
    float* ws  = (float*)d_ws;

    float* p        = ws;                     // 8192
    float* s        = ws + 8192;              // 128
    unsigned* mm    = (unsigned*)(ws + 8448); // 2
    unsigned* hist  = (unsigned*)(ws + 8456); // 128

    pool_kernel<<<512, 256, 0, stream>>>(x, p);
    mid_kernel<<<1, 1024, 0, stream>>>(p, w1, w2, s, mm, hist);
    gated_minmax_kernel<<<512, 256, 0, stream>>>(x, s, mm);
    gated_hist_kernel<<<512, 256, 0, stream>>>(x, s, mm, hist);
    entropy_kernel<<<1, 64, 0, stream>>>(hist, out);
}